// Round 7
// baseline (954.434 us; speedup 1.0000x reference)
//
#include <hip/hip_runtime.h>

#define ZDIM 4096
#define DIN  256
#define DTS  2048
#define DOUT 256
#define CDIM 65536
#define SPLIT 16
#define CHUNK (CDIM / SPLIT)   // 4096 c per chunk = 16 i of 256 j
#define ZP    128              // z rows per block

typedef float fv4 __attribute__((ext_vector_type(4)));
typedef __bf16 bv8 __attribute__((ext_vector_type(8)));
typedef unsigned short u16;
typedef u16 uv8 __attribute__((ext_vector_type(8)));
typedef u16 uv4 __attribute__((ext_vector_type(4)));

union BC  { __bf16 b; u16 u; };
union VC8 { uv8 u; bv8 b; };
union FU  { unsigned u; float f; };

static __device__ __forceinline__ u16  f2b(float f){ BC c; c.b=(__bf16)f; return c.u; }
static __device__ __forceinline__ float bu(u16 v){ FU c; c.u = ((unsigned)v) << 16; return c.f; }
static __device__ __forceinline__ bv8  asb(uv8 x){ VC8 c; c.u=x; return c.b; }
static __device__ __forceinline__ uv8  pack8(fv4 a, fv4 b){
  uv8 p;
  p[0]=f2b(a[0]); p[1]=f2b(a[1]); p[2]=f2b(a[2]); p[3]=f2b(a[3]);
  p[4]=f2b(b[0]); p[5]=f2b(b[1]); p[6]=f2b(b[2]); p[7]=f2b(b[3]);
  return p;
}

// ---------------------------------------------------------------------------
// Kernel 1: Kmat[k][c] = sum_t W[k][t] * T[t][c]   (bf16 output in ws)
// memory-bound: streams 512 MB of T once. Unchanged (attribution).
// ---------------------------------------------------------------------------
__global__ __launch_bounds__(512, 2) void k_wt(const float* __restrict__ W,
                                               const float* __restrict__ T,
                                               u16* __restrict__ Km) {
  __shared__ u16 Al[256 * 40];
  __shared__ u16 Bl[32 * 128];
  const int tid  = threadIdx.x;
  const int lane = tid & 63;
  const int wave = tid >> 6;
  const int wk = (wave >> 1) * 64;
  const int wc = (wave & 1) * 64;
  const int cb = blockIdx.x * 128;
  const int ar = lane & 15, tg = lane >> 4;

  fv4 acc[4][4];
#pragma unroll
  for (int m = 0; m < 4; ++m)
#pragma unroll
    for (int n = 0; n < 4; ++n)
#pragma unroll
      for (int r = 0; r < 4; ++r) acc[m][n][r] = 0.f;

  for (int t0 = 0; t0 < DTS; t0 += 32) {
#pragma unroll
    for (int p = 0; p < 2; ++p) {
      int oct = tid + p * 512;
      int kr = oct >> 2, ts = (oct & 3) * 8;
      const float* src = W + (size_t)kr * DTS + t0 + ts;
      fv4 a = *(const fv4*)src, b = *(const fv4*)(src + 4);
      *(uv8*)&Al[kr * 40 + ts] = pack8(a, b);
    }
    {
      int tr = tid >> 4, co = (tid & 15) * 8;
      const float* src = T + (size_t)(t0 + tr) * CDIM + cb + co;
      fv4 a = *(const fv4*)src, b = *(const fv4*)(src + 4);
      *(uv8*)&Bl[tr * 128 + co] = pack8(a, b);
    }
    __syncthreads();
    bv8 af[4];
#pragma unroll
    for (int m = 0; m < 4; ++m)
      af[m] = asb(*(const uv8*)&Al[(wk + m * 16 + ar) * 40 + tg * 8]);
#pragma unroll
    for (int n = 0; n < 4; ++n) {
      uv8 bu2;
#pragma unroll
      for (int e = 0; e < 8; ++e)
        bu2[e] = Bl[(tg * 8 + e) * 128 + wc + n * 16 + ar];
      bv8 bf = asb(bu2);
#pragma unroll
      for (int m = 0; m < 4; ++m)
        acc[m][n] = __builtin_amdgcn_mfma_f32_16x16x32_bf16(af[m], bf, acc[m][n], 0, 0, 0);
    }
    __syncthreads();
  }
#pragma unroll
  for (int m = 0; m < 4; ++m)
#pragma unroll
    for (int n = 0; n < 4; ++n)
#pragma unroll
      for (int r = 0; r < 4; ++r) {
        int kr = wk + m * 16 + tg * 4 + r;
        int cc = cb + wc + n * 16 + ar;
        Km[(size_t)kr * CDIM + cc] = f2b(acc[m][n][r]);
      }
}

// ---------------------------------------------------------------------------
// Kernel 2 v7: identical compute structure to v6 (128 VGPR clean), but:
//   SPLIT=16 -> grid 512 = 2 blocks/CU (cross-block TLP hides stage latency);
//   chunk = 4096 c (128 stages); Xt 8 KB; LDS 44 KB total;
//   partial P stored bf16 (2 MB per split, 32 MB total).
// s = bid&15: XCD (s&7) hosts chunks {s, s+8} -> 4 MB same-XCD working set.
// 8 waves = 2(z) x 4(k); wave tile 64z x 64k; 16 MFMA per barrier.
// ---------------------------------------------------------------------------
__global__ __launch_bounds__(512, 2) void k_bil(const float* __restrict__ X,
                                                const u16* __restrict__ Km,
                                                u16* __restrict__ P) {
  __shared__ u16 Kl[2][256 * 36];   // 2 x 18 KB: [k][32 j], pad 36
  __shared__ float Xt[16 * ZP];     // 8 KB: Xt[i][z] = X[z0+z][i0+i]
  const int tid  = threadIdx.x;
  const int lane = tid & 63;
  const int wave = tid >> 6;
  const int wz   = (wave >> 2) * 64;   // z-half
  const int wk   = (wave & 3) * 64;    // k-quarter
  const int bid  = blockIdx.x;
  const int s    = bid & 15;           // chunk; XCD s&7 hosts chunks {s, s+8}
  const int z0   = (bid >> 4) * ZP;
  const int i0   = s * 16;
  const int cs   = s * CHUNK;
  const int ar = lane & 15, tg = lane >> 4;

  // one-time Xt stage (f32 xi for exactness)
  for (int idx = tid; idx < 16 * ZP; idx += 512) {
    int ii = idx >> 7, z = idx & (ZP - 1);
    Xt[idx] = X[(size_t)(z0 + z) * DIN + i0 + ii];
  }

  // A-base fragments: af[m][js] = bf16(x[z0+wz+m*16+ar][js*32+tg*8 .. +8])
  uv8 af[4][8];
#pragma unroll
  for (int m = 0; m < 4; ++m) {
    const float* row = X + (size_t)(z0 + wz + m * 16 + ar) * DIN;
#pragma unroll
    for (int js = 0; js < 8; ++js) {
      const float* src = row + js * 32 + tg * 8;
      fv4 a = *(const fv4*)src, b = *(const fv4*)(src + 4);
      af[m][js] = pack8(a, b);
    }
  }

  // B staging map: thread t -> k row t>>1, 16-elem j-seg (t&1)*16
  const int sk = tid >> 1, sj = (tid & 1) * 16;
  const u16* gb = Km + (size_t)sk * CDIM + cs + sj;

  // prologue: stage 0
  {
    uv8 a = *(const uv8*)gb, b = *(const uv8*)(gb + 8);
    *(uv8*)&Kl[0][sk * 36 + sj]     = a;
    *(uv8*)&Kl[0][sk * 36 + sj + 8] = b;
  }
  __syncthreads();

  fv4 acc[4][4];
#pragma unroll
  for (int m = 0; m < 4; ++m)
#pragma unroll
    for (int n = 0; n < 4; ++n)
#pragma unroll
      for (int r = 0; r < 4; ++r) acc[m][n][r] = 0.f;

  int buf = 0;
  for (int i = 0; i < 16; ++i) {
    float xi[4];
#pragma unroll
    for (int m = 0; m < 4; ++m) xi[m] = Xt[i * ZP + wz + m * 16 + ar];
#pragma unroll
    for (int js = 0; js < 8; ++js) {
      const int st = i * 8 + js;
      const bool stg = (st < 127);
      uv8 g0, g1;
      if (stg) {                       // issue next-stage loads early
        const u16* p = gb + (size_t)(st + 1) * 32;
        g0 = *(const uv8*)p;
        g1 = *(const uv8*)(p + 8);
      }
      bv8 bf[4];
#pragma unroll
      for (int n = 0; n < 4; ++n)
        bf[n] = asb(*(const uv8*)&Kl[buf][(wk + n * 16 + ar) * 36 + tg * 8]);
#pragma unroll
      for (int m = 0; m < 4; ++m) {
        uv8 ap;
#pragma unroll
        for (int e = 0; e < 8; ++e) ap[e] = f2b(xi[m] * bu(af[m][js][e]));
        bv8 apb = asb(ap);
#pragma unroll
        for (int n = 0; n < 4; ++n)
          acc[m][n] = __builtin_amdgcn_mfma_f32_16x16x32_bf16(apb, bf[n], acc[m][n], 0, 0, 0);
      }
      if (stg) {                       // write-late into other buffer
        u16* d = &Kl[buf ^ 1][sk * 36 + sj];
        *(uv8*)d       = g0;
        *(uv8*)(d + 8) = g1;
      }
      __syncthreads();
      buf ^= 1;
    }
  }

  u16* dst = P + (size_t)s * (ZDIM * DOUT) + (size_t)z0 * DOUT;
#pragma unroll
  for (int m = 0; m < 4; ++m)
#pragma unroll
    for (int n = 0; n < 4; ++n)
#pragma unroll
      for (int r = 0; r < 4; ++r)
        dst[(size_t)(wz + m * 16 + tg * 4 + r) * DOUT + wk + n * 16 + ar] =
            f2b(acc[m][n][r]);
}

// ---------------------------------------------------------------------------
// Kernel 3: out[z][k] = sum_s bf16 partial[s][z][k]
// ---------------------------------------------------------------------------
__global__ __launch_bounds__(256) void k_red(const u16* __restrict__ P,
                                             float* __restrict__ O) {
  size_t idx = ((size_t)blockIdx.x * 256 + threadIdx.x) * 4;
  fv4 acc;
#pragma unroll
  for (int r = 0; r < 4; ++r) acc[r] = 0.f;
#pragma unroll
  for (int p = 0; p < SPLIT; ++p) {
    uv4 v = *(const uv4*)&P[(size_t)p * (ZDIM * DOUT) + idx];
#pragma unroll
    for (int r = 0; r < 4; ++r) acc[r] += bu(v[r]);
  }
  *(fv4*)&O[idx] = acc;
}

extern "C" void kernel_launch(void* const* d_in, const int* in_sizes, int n_in,
                              void* d_out, int out_size, void* d_ws, size_t ws_size,
                              hipStream_t stream) {
  const float* feat = (const float*)d_in[0];   // [4096, 256]
  const float* T    = (const float*)d_in[1];   // [2048, 65536]
  const float* W    = (const float*)d_in[2];   // [256, 2048]
  float* out = (float*)d_out;                  // [4096, 256]

  u16* Km = (u16*)d_ws;                                      // 32 MB bf16 Kmat
  u16* P  = (u16*)((char*)d_ws + (size_t)DOUT * CDIM * 2);   // 32 MB bf16 partials

  k_wt <<<dim3(512),  dim3(512), 0, stream>>>(W, T, Km);
  k_bil<<<dim3(512),  dim3(512), 0, stream>>>(feat, Km, P);
  k_red<<<dim3(1024), dim3(256), 0, stream>>>(P, out);
}

// Round 9
// 342.709 us; speedup vs baseline: 2.7850x; 2.7850x over previous
//
#include <hip/hip_runtime.h>

#define ZDIM 4096
#define DIN  256
#define DTS  2048
#define DOUT 256
#define CDIM 65536
#define SPLIT 16
#define NJS  8                 // j super-blocks of 32 (j in [0,256))
#define NI   16                // i per chunk (i_glob in chunk s: s*16..s*16+16)
#define NST  (NJS * NI)        // 128 stage tiles per chunk
#define ZP   256               // z rows per k_bil block
#define TILE_B 16384           // 256 k x 32 j x 2B per stage tile

typedef float fv4 __attribute__((ext_vector_type(4)));
typedef __bf16 bv8 __attribute__((ext_vector_type(8)));
typedef unsigned short u16;
typedef u16 uv8 __attribute__((ext_vector_type(8)));
typedef u16 uv4 __attribute__((ext_vector_type(4)));

union BC  { __bf16 b; u16 u; };
union VC8 { uv8 u; bv8 b; };
union FU  { unsigned u; float f; };

static __device__ __forceinline__ u16  f2b(float f){ BC c; c.b=(__bf16)f; return c.u; }
static __device__ __forceinline__ float bu(u16 v){ FU c; c.u = ((unsigned)v) << 16; return c.f; }
static __device__ __forceinline__ bv8  asb(uv8 x){ VC8 c; c.u=x; return c.b; }
static __device__ __forceinline__ uv8  pack8(fv4 a, fv4 b){
  uv8 p;
  p[0]=f2b(a[0]); p[1]=f2b(a[1]); p[2]=f2b(a[2]); p[3]=f2b(a[3]);
  p[4]=f2b(b[0]); p[5]=f2b(b[1]); p[6]=f2b(b[2]); p[7]=f2b(b[3]);
  return p;
}

// Km tiled layout: tile_id = s*128 + js*16 + i_loc  (s = i_glob>>4, i_loc = i_glob&15,
// js = j>>5). Within a 16KB tile, element (k, jj) at byte
//   e = k*64 + jj*2;  e ^= ((e>>7)&7)<<4;   // bank swizzle for b128 reads

// ---------------------------------------------------------------------------
// Kernel 1: Kmat = W @ T -> bf16, written in the TILED+SWIZZLED layout above.
// memory-bound: streams 512 MB of T once.
// ---------------------------------------------------------------------------
__global__ __launch_bounds__(512, 2) void k_wt(const float* __restrict__ W,
                                               const float* __restrict__ T,
                                               u16* __restrict__ Km) {
  __shared__ u16 Al[256 * 40];
  __shared__ u16 Bl[32 * 128];
  const int tid  = threadIdx.x;
  const int lane = tid & 63;
  const int wave = tid >> 6;
  const int wk = (wave >> 1) * 64;
  const int wc = (wave & 1) * 64;
  const int cb = blockIdx.x * 128;
  const int ar = lane & 15, tg = lane >> 4;

  fv4 acc[4][4];
#pragma unroll
  for (int m = 0; m < 4; ++m)
#pragma unroll
    for (int n = 0; n < 4; ++n)
#pragma unroll
      for (int r = 0; r < 4; ++r) acc[m][n][r] = 0.f;

  for (int t0 = 0; t0 < DTS; t0 += 32) {
#pragma unroll
    for (int p = 0; p < 2; ++p) {
      int oct = tid + p * 512;
      int kr = oct >> 2, ts = (oct & 3) * 8;
      const float* src = W + (size_t)kr * DTS + t0 + ts;
      fv4 a = *(const fv4*)src, b = *(const fv4*)(src + 4);
      *(uv8*)&Al[kr * 40 + ts] = pack8(a, b);
    }
    {
      int tr = tid >> 4, co = (tid & 15) * 8;
      const float* src = T + (size_t)(t0 + tr) * CDIM + cb + co;
      fv4 a = *(const fv4*)src, b = *(const fv4*)(src + 4);
      *(uv8*)&Bl[tr * 128 + co] = pack8(a, b);
    }
    __syncthreads();
    bv8 af[4];
#pragma unroll
    for (int m = 0; m < 4; ++m)
      af[m] = asb(*(const uv8*)&Al[(wk + m * 16 + ar) * 40 + tg * 8]);
#pragma unroll
    for (int n = 0; n < 4; ++n) {
      uv8 bu2;
#pragma unroll
      for (int e = 0; e < 8; ++e)
        bu2[e] = Bl[(tg * 8 + e) * 128 + wc + n * 16 + ar];
      bv8 bf = asb(bu2);
#pragma unroll
      for (int m = 0; m < 4; ++m)
        acc[m][n] = __builtin_amdgcn_mfma_f32_16x16x32_bf16(af[m], bf, acc[m][n], 0, 0, 0);
    }
    __syncthreads();
  }
  // epilogue: write tiled + swizzled
  const int ig = cb >> 8;            // i_glob (cb multiple of 128 -> fixed ig)
  const int j0 = cb & 255;           // 0 or 128
#pragma unroll
  for (int m = 0; m < 4; ++m)
#pragma unroll
    for (int n = 0; n < 4; ++n) {
      int j  = j0 + wc + n * 16;     // lane-uniform j base (ar adds 0..15)
      int js = j >> 5;
      int jj = j & 31;               // + ar stays < 32 (base 16-aligned)
      int sc = ig >> 4, il = ig & 15;
      size_t tb = ((size_t)(sc * 128 + js * 16 + il)) * TILE_B;
#pragma unroll
      for (int r = 0; r < 4; ++r) {
        int kr = wk + m * 16 + tg * 4 + r;
        int e  = kr * 64 + (jj + ar) * 2;
        e ^= ((e >> 7) & 7) << 4;
        *(u16*)((char*)Km + tb + e) = f2b(acc[m][n][r]);
      }
    }
}

// ---------------------------------------------------------------------------
// Kernel 2 v8: out[z,k] = sum_i x_i * sum_j x_j Km[k, i*256+j]
// j-outer / i-inner: A-frag (64z x 32j per wave) constant over 16 i-stages.
// Km streamed CONTIGUOUSLY (tiled layout) via global_load_lds width 16.
// grid 256 = 16 chunks x 16 z-tiles (ZP=256); block 1024 = 16 waves (4z x 4k);
// wave tile 64z x 64k; 16 MFMA per stage; ~120 VGPR; LDS 60 KB.
// ---------------------------------------------------------------------------
__global__ __launch_bounds__(1024) void k_bil(const float* __restrict__ X,
                                              const u16* __restrict__ Km,
                                              u16* __restrict__ P) {
  __shared__ u16 Kl[2][TILE_B / 2];   // 2 x 16KB swizzled stage tiles
  __shared__ u16 Xb[256 * 40];        // 20KB: x[z][32 j-in-block] bf16, pad 40
  __shared__ u16 Xt[256 * 16];        // 8KB:  x[z][16 i-in-chunk] bf16
  const int tid  = threadIdx.x;
  const int lane = tid & 63;
  const int wave = tid >> 6;           // 0..15
  const int wz   = (wave >> 2) * 64;
  const int wk   = (wave & 3) * 64;
  const int bid  = blockIdx.x;
  const int s    = bid & 15;
  const int z0   = (bid >> 4) * ZP;
  const int i0   = s * NI;
  const int ar   = lane & 15, tg = lane >> 4;

  const char* chunk = (const char*)Km + (size_t)s * NST * TILE_B;

  // one-time Xt stage: x[z][i0..i0+16] as bf16 (contiguous 16B per thread)
  {
    int z = tid >> 2, ip = (tid & 3) * 4;
    fv4 v = *(const fv4*)&X[(size_t)(z0 + z) * DIN + i0 + ip];
    uv4 o;
#pragma unroll
    for (int e = 0; e < 4; ++e) o[e] = f2b(v[e]);
    *(uv4*)&Xt[z * 16 + ip] = o;
  }
  // prologue: tile 0 -> Kl[0] (contiguous 16KB, 16B per thread)
  __builtin_amdgcn_global_load_lds(
      (const __attribute__((address_space(1))) void*)(chunk + (size_t)tid * 16),
      (__attribute__((address_space(3))) void*)((char*)&Kl[0][0] + tid * 16),
      16, 0, 0);

  // loop-invariant LDS offsets
  int boff[4], aoff[4], xoff[4];
#pragma unroll
  for (int n = 0; n < 4; ++n) {
    int k = wk + n * 16 + ar;
    int e = k * 64 + tg * 16;
    boff[n] = e ^ (((e >> 7) & 7) << 4);
  }
#pragma unroll
  for (int m = 0; m < 4; ++m) {
    aoff[m] = (wz + m * 16 + ar) * 40 + tg * 8;   // u16 units
    xoff[m] = (wz + m * 16 + ar) * 16;            // u16 units
  }

  fv4 acc[4][4];
#pragma unroll
  for (int m = 0; m < 4; ++m)
#pragma unroll
    for (int n = 0; n < 4; ++n)
#pragma unroll
      for (int r = 0; r < 4; ++r) acc[m][n][r] = 0.f;

  for (int js = 0; js < NJS; ++js) {
    // stage Xb for this js (32 j columns of x, bf16)
    {
      int z = tid >> 2, seg = (tid & 3) * 8;
      const float* src = &X[(size_t)(z0 + z) * DIN + js * 32 + seg];
      fv4 a = *(const fv4*)src, b = *(const fv4*)(src + 4);
      *(uv8*)&Xb[z * 40 + seg] = pack8(a, b);
    }
    __syncthreads();   // Xb ready (also covers Xt/tile0 on js=0)

    uv8 af[4];
#pragma unroll
    for (int m = 0; m < 4; ++m)
      af[m] = *(const uv8*)&Xb[aoff[m]];

    for (int i = 0; i < NI; ++i) {
      const int st = js * NI + i;
      if (st + 1 < NST)
        __builtin_amdgcn_global_load_lds(
            (const __attribute__((address_space(1))) void*)(chunk + (size_t)(st + 1) * TILE_B + (size_t)tid * 16),
            (__attribute__((address_space(3))) void*)((char*)&Kl[(st + 1) & 1][0] + tid * 16),
            16, 0, 0);
      float xi[4];
#pragma unroll
      for (int m = 0; m < 4; ++m) xi[m] = bu(Xt[xoff[m] + i]);
      const char* kb = (const char*)&Kl[st & 1][0];
      bv8 bf[4];
#pragma unroll
      for (int n = 0; n < 4; ++n)
        bf[n] = asb(*(const uv8*)(kb + boff[n]));
#pragma unroll
      for (int m = 0; m < 4; ++m) {
        uv8 ap;
#pragma unroll
        for (int e = 0; e < 8; ++e) ap[e] = f2b(xi[m] * bu(af[m][e]));
        bv8 apb = asb(ap);
#pragma unroll
        for (int n = 0; n < 4; ++n)
          acc[m][n] = __builtin_amdgcn_mfma_f32_16x16x32_bf16(apb, bf[n], acc[m][n], 0, 0, 0);
      }
      __syncthreads();   // next tile landed; all waves done with Kl[st&1]
    }
  }

  u16* dst = P + (size_t)s * (ZDIM * DOUT) + (size_t)z0 * DOUT;
#pragma unroll
  for (int m = 0; m < 4; ++m)
#pragma unroll
    for (int n = 0; n < 4; ++n)
#pragma unroll
      for (int r = 0; r < 4; ++r)
        dst[(size_t)(wz + m * 16 + tg * 4 + r) * DOUT + wk + n * 16 + ar] =
            f2b(acc[m][n][r]);
}

// ---------------------------------------------------------------------------
// Kernel 3: out[z][k] = sum_s bf16 partial[s][z][k]
// ---------------------------------------------------------------------------
__global__ __launch_bounds__(256) void k_red(const u16* __restrict__ P,
                                             float* __restrict__ O) {
  size_t idx = ((size_t)blockIdx.x * 256 + threadIdx.x) * 4;
  fv4 acc;
#pragma unroll
  for (int r = 0; r < 4; ++r) acc[r] = 0.f;
#pragma unroll
  for (int p = 0; p < SPLIT; ++p) {
    uv4 v = *(const uv4*)&P[(size_t)p * (ZDIM * DOUT) + idx];
#pragma unroll
    for (int r = 0; r < 4; ++r) acc[r] += bu(v[r]);
  }
  *(fv4*)&O[idx] = acc;
}

extern "C" void kernel_launch(void* const* d_in, const int* in_sizes, int n_in,
                              void* d_out, int out_size, void* d_ws, size_t ws_size,
                              hipStream_t stream) {
  const float* feat = (const float*)d_in[0];   // [4096, 256]
  const float* T    = (const float*)d_in[1];   // [2048, 65536]
  const float* W    = (const float*)d_in[2];   // [256, 2048]
  float* out = (float*)d_out;                  // [4096, 256]

  u16* Km = (u16*)d_ws;                                      // 32 MB bf16 tiled Kmat
  u16* P  = (u16*)((char*)d_ws + (size_t)DOUT * CDIM * 2);   // 32 MB bf16 partials

  k_wt <<<dim3(512),  dim3(512),  0, stream>>>(W, T, Km);
  k_bil<<<dim3(256),  dim3(1024), 0, stream>>>(feat, Km, P);
  k_red<<<dim3(1024), dim3(256),  0, stream>>>(P, out);
}